// Round 1
// baseline (621.246 us; speedup 1.0000x reference)
//
#include <hip/hip_runtime.h>
#include <cstddef>
#include <cstdint>

#define NN 50000
#define NE 800000
#define CH 128
#define NBLK ((NN + 255) / 256)   // 196

// ---------------- scan helpers ----------------
__device__ __forceinline__ int wave_scan_incl(int v) {
  int lane = threadIdx.x & 63;
#pragma unroll
  for (int d = 1; d < 64; d <<= 1) {
    int u = __shfl_up(v, d, 64);
    if (lane >= d) v += u;
  }
  return v;
}

__device__ __forceinline__ int block_scan_incl(int v, int* wsum) {
  int t = threadIdx.x, lane = t & 63, wid = t >> 6;
  int incl = wave_scan_incl(v);
  if (lane == 63) wsum[wid] = incl;
  __syncthreads();
  int add = 0;
#pragma unroll
  for (int w = 0; w < 3; ++w) add += (w < wid) ? wsum[w] : 0;
  return incl + add;
}

// ---------------- CSR build ----------------
__global__ __launch_bounds__(256) void k_zero(float* __restrict__ deg, int* __restrict__ cur) {
  int i = blockIdx.x * 256 + threadIdx.x;
  if (i < NN) { deg[i] = 0.f; cur[i] = 0; }
}

__global__ __launch_bounds__(256) void k_deg_cnt(const int* __restrict__ ei, const float* __restrict__ ew,
                                                 float* __restrict__ deg, int* __restrict__ cnt) {
  int e = blockIdx.x * 256 + threadIdx.x;
  if (e >= NE) return;
  atomicAdd(&deg[ei[e]], ew[e]);
  atomicAdd(&cnt[ei[NE + e]], 1);
}

__global__ __launch_bounds__(256) void k_dis(const float* __restrict__ deg, float* __restrict__ dis) {
  int i = blockIdx.x * 256 + threadIdx.x;
  if (i < NN) { float d = deg[i]; dis[i] = (d > 0.f) ? rsqrtf(d) : 0.f; }
}

__global__ __launch_bounds__(256) void k_scan1(const int* __restrict__ cnt, int* __restrict__ partials) {
  __shared__ int wsum[4];
  int i = blockIdx.x * 256 + threadIdx.x;
  int v = (i < NN) ? cnt[i] : 0;
  int incl = block_scan_incl(v, wsum);
  if (threadIdx.x == 255) partials[blockIdx.x] = incl;
}

__global__ __launch_bounds__(256) void k_scan2(int* __restrict__ partials, int* __restrict__ rp_last) {
  __shared__ int wsum[4];
  int t = threadIdx.x;
  int v = (t < NBLK) ? partials[t] : 0;
  int incl = block_scan_incl(v, wsum);
  if (t < NBLK) partials[t] = incl - v;     // exclusive block offset
  if (t == 255) rp_last[0] = incl;          // total == NE
}

__global__ __launch_bounds__(256) void k_scan3(int* __restrict__ cnt_cur, const int* __restrict__ partials,
                                               int* __restrict__ rp) {
  __shared__ int wsum[4];
  int i = blockIdx.x * 256 + threadIdx.x;
  int v = (i < NN) ? cnt_cur[i] : 0;
  int incl = block_scan_incl(v, wsum);
  int excl = incl - v + partials[blockIdx.x];
  if (i < NN) { rp[i] = excl; cnt_cur[i] = excl; }  // cnt_cur becomes insert cursor
}

__global__ __launch_bounds__(256) void k_fill(const int* __restrict__ ei, const float* __restrict__ ew,
                                              const float* __restrict__ dis, int* __restrict__ cur,
                                              int* __restrict__ src, float* __restrict__ wv) {
  int e = blockIdx.x * 256 + threadIdx.x;
  if (e >= NE) return;
  int r = ei[e], c = ei[NE + e];
  float w = dis[r] * ew[e] * dis[c];
  int p = atomicAdd(&cur[c], 1);
  src[p] = r;
  wv[p] = w;
}

// ---------------- propagation (gather) ----------------
// out[node,ch] = coefP * sum_j wv[j]*h[src[j],ch]  + (other ? coefO*other[node,ch] : 0)
__global__ __launch_bounds__(128) void k_prop(const int* __restrict__ rp, const int* __restrict__ src,
                                              const float* __restrict__ wv, const float* __restrict__ h,
                                              const float* __restrict__ other, float* __restrict__ out,
                                              const float coefP, const float coefO) {
  __shared__ int s_src[128];
  __shared__ float s_wv[128];
  const int node = blockIdx.x;
  const int t = threadIdx.x;
  const int j0 = rp[node], j1 = rp[node + 1];
  float acc = 0.f;
  for (int base = j0; base < j1; base += 128) {
    int cnt = j1 - base; if (cnt > 128) cnt = 128;
    __syncthreads();
    if (t < cnt) { s_src[t] = src[base + t]; s_wv[t] = wv[base + t]; }
    __syncthreads();
#pragma unroll 4
    for (int j = 0; j < cnt; ++j) {
      acc = fmaf(s_wv[j], h[(size_t)s_src[j] * CH + t], acc);
    }
  }
  const size_t idx = (size_t)node * CH + t;
  float o = (other != nullptr) ? coefO * other[idx] : 0.f;
  out[idx] = fmaf(coefP, acc, o);
}

// ---------------- GEMM: Cd (+)= A[NN x 128] * B[128 x 128], optional bias+relu ----------------
// mode bit0: accumulate into Cd; bit1: final (add bias, relu)
__global__ __launch_bounds__(256) void k_gemm(const float* __restrict__ A,
                                              const float* __restrict__ B,
                                              float* __restrict__ Cd,
                                              const float* __restrict__ bias,
                                              const int mode) {
  __shared__ float As[64][68];
  __shared__ float Bs[64][64];
  const int tid = threadIdx.x;
  const int brow = blockIdx.x << 6;
  const int bcol = blockIdx.y << 6;
  const int r0 = (tid >> 4) << 2;
  const int c0 = (tid & 15) << 2;
  float acc[4][4] = {{0.f,0.f,0.f,0.f},{0.f,0.f,0.f,0.f},{0.f,0.f,0.f,0.f},{0.f,0.f,0.f,0.f}};
#pragma unroll
  for (int ck = 0; ck < 2; ++ck) {
    if (ck) __syncthreads();
#pragma unroll
    for (int it = 0; it < 4; ++it) {
      const int lin = (it * 256 + tid) * 4;   // 0..4095
      const int rr = lin >> 6;                // 0..63
      const int kk = lin & 63;                // multiple of 4
      float4 av = make_float4(0.f, 0.f, 0.f, 0.f);
      if (brow + rr < NN)
        av = *(const float4*)&A[(size_t)(brow + rr) * CH + (ck * 64 + kk)];
      *(float4*)&As[rr][kk] = av;
      const float4 bv = *(const float4*)&B[(size_t)(ck * 64 + rr) * CH + (bcol + kk)];
      *(float4*)&Bs[rr][kk] = bv;
    }
    __syncthreads();
#pragma unroll 8
    for (int kk = 0; kk < 64; ++kk) {
      const float a0 = As[r0 + 0][kk];
      const float a1 = As[r0 + 1][kk];
      const float a2 = As[r0 + 2][kk];
      const float a3 = As[r0 + 3][kk];
      const float4 b = *(const float4*)&Bs[kk][c0];
      acc[0][0] = fmaf(a0, b.x, acc[0][0]); acc[0][1] = fmaf(a0, b.y, acc[0][1]);
      acc[0][2] = fmaf(a0, b.z, acc[0][2]); acc[0][3] = fmaf(a0, b.w, acc[0][3]);
      acc[1][0] = fmaf(a1, b.x, acc[1][0]); acc[1][1] = fmaf(a1, b.y, acc[1][1]);
      acc[1][2] = fmaf(a1, b.z, acc[1][2]); acc[1][3] = fmaf(a1, b.w, acc[1][3]);
      acc[2][0] = fmaf(a2, b.x, acc[2][0]); acc[2][1] = fmaf(a2, b.y, acc[2][1]);
      acc[2][2] = fmaf(a2, b.z, acc[2][2]); acc[2][3] = fmaf(a2, b.w, acc[2][3]);
      acc[3][0] = fmaf(a3, b.x, acc[3][0]); acc[3][1] = fmaf(a3, b.y, acc[3][1]);
      acc[3][2] = fmaf(a3, b.z, acc[3][2]); acc[3][3] = fmaf(a3, b.w, acc[3][3]);
    }
  }
#pragma unroll
  for (int i = 0; i < 4; ++i) {
    const int row = brow + r0 + i;
    if (row >= NN) continue;
    const size_t off = (size_t)row * CH + bcol + c0;
    float4 v = make_float4(acc[i][0], acc[i][1], acc[i][2], acc[i][3]);
    if (mode & 1) {
      const float4 p = *(const float4*)&Cd[off];
      v.x += p.x; v.y += p.y; v.z += p.z; v.w += p.w;
    }
    if (mode & 2) {
      const float4 bb = *(const float4*)&bias[bcol + c0];
      v.x = fmaxf(v.x + bb.x, 0.f); v.y = fmaxf(v.y + bb.y, 0.f);
      v.z = fmaxf(v.z + bb.z, 0.f); v.w = fmaxf(v.w + bb.w, 0.f);
    }
    *(float4*)&Cd[off] = v;
  }
}

// ---------------- launch ----------------
static inline size_t align256(size_t x) { return (x + 255) & ~(size_t)255; }

extern "C" void kernel_launch(void* const* d_in, const int* in_sizes, int n_in,
                              void* d_out, int out_size, void* d_ws, size_t ws_size,
                              hipStream_t stream) {
  const float* x  = (const float*)d_in[0];
  const int*   ei = (const int*)d_in[1];
  const float* ew = (const float*)d_in[2];
  const float* W[4]  = {(const float*)d_in[3], (const float*)d_in[5],
                        (const float*)d_in[7], (const float*)d_in[9]};
  const float* bs[4] = {(const float*)d_in[4], (const float*)d_in[6],
                        (const float*)d_in[8], (const float*)d_in[10]};
  float* out = (float*)d_out;

  char* ws = (char*)d_ws;
  size_t off = 0;
  auto alloc = [&](size_t bytes) -> void* { void* p = ws + off; off = align256(off + bytes); return p; };
  float* deg      = (float*)alloc(sizeof(float) * NN);
  float* dis      = (float*)alloc(sizeof(float) * NN);
  int*   rp       = (int*)alloc(sizeof(int) * (NN + 1));
  int*   cur      = (int*)alloc(sizeof(int) * NN);     // doubles as count, then cursor
  int*   partials = (int*)alloc(sizeof(int) * 256);
  int*   srcv     = (int*)alloc(sizeof(int) * NE);
  float* wvv      = (float*)alloc(sizeof(float) * NE);
  float* buf1     = (float*)alloc(sizeof(float) * (size_t)NN * CH);
  float* buf2     = (float*)alloc(sizeof(float) * (size_t)NN * CH);
  (void)ws_size; (void)in_sizes; (void)n_in; (void)out_size;

  const int bE = (NE + 255) / 256;
  const int bN = NBLK;

  // CSR build
  k_zero<<<bN, 256, 0, stream>>>(deg, cur);
  k_deg_cnt<<<bE, 256, 0, stream>>>(ei, ew, deg, cur);
  k_dis<<<bN, 256, 0, stream>>>(deg, dis);
  k_scan1<<<bN, 256, 0, stream>>>(cur, partials);
  k_scan2<<<1, 256, 0, stream>>>(partials, rp + NN);
  k_scan3<<<bN, 256, 0, stream>>>(cur, partials, rp);
  k_fill<<<bE, 256, 0, stream>>>(ei, ew, dis, cur, srcv, wvv);

  const size_t OC = (size_t)NN * CH;
  dim3 gg((NN + 63) / 64, 2);

  // pass k=0: A = Tx0 = x
  k_gemm<<<gg, 256, 0, stream>>>(x, W[0], out,          bs[0], 2); // out0: init+final
  k_gemm<<<gg, 256, 0, stream>>>(x, W[1], out + OC,     bs[1], 0);
  k_gemm<<<gg, 256, 0, stream>>>(x, W[2], out + 2 * OC, bs[2], 0);
  k_gemm<<<gg, 256, 0, stream>>>(x, W[3], out + 3 * OC, bs[3], 0);

  // Tx1 = -P(x)
  k_prop<<<NN, 128, 0, stream>>>(rp, srcv, wvv, x, nullptr, buf1, -1.f, 0.f);

  // pass k=1: A = Tx1 (buf1)
  k_gemm<<<gg, 256, 0, stream>>>(buf1, W[1] + 1 * CH * CH, out + OC,     bs[1], 3);
  k_gemm<<<gg, 256, 0, stream>>>(buf1, W[2] + 1 * CH * CH, out + 2 * OC, bs[2], 1);
  k_gemm<<<gg, 256, 0, stream>>>(buf1, W[3] + 1 * CH * CH, out + 3 * OC, bs[3], 1);

  // Tx2 = -1.5 P(Tx1) - 0.5 x   -> buf2
  k_prop<<<NN, 128, 0, stream>>>(rp, srcv, wvv, buf1, x, buf2, -1.5f, -0.5f);

  // pass k=2: A = Tx2 (buf2)
  k_gemm<<<gg, 256, 0, stream>>>(buf2, W[2] + 2 * CH * CH, out + 2 * OC, bs[2], 3);
  k_gemm<<<gg, 256, 0, stream>>>(buf2, W[3] + 2 * CH * CH, out + 3 * OC, bs[3], 1);

  // Tx3 = -(5/3) P(Tx2) - (2/3) Tx1   -> buf1 (in-place safe: per-thread same-index RMW)
  k_prop<<<NN, 128, 0, stream>>>(rp, srcv, wvv, buf2, buf1, buf1, -5.f / 3.f, -2.f / 3.f);

  // pass k=3: A = Tx3 (buf1)
  k_gemm<<<gg, 256, 0, stream>>>(buf1, W[3] + 3 * CH * CH, out + 3 * OC, bs[3], 3);
}

// Round 2
// 316.497 us; speedup vs baseline: 1.9629x; 1.9629x over previous
//
#include <hip/hip_runtime.h>
#include <cstddef>
#include <cstdint>

#define NN 50000
#define NE 800000
#define CH 128
#define NBLK ((NN + 255) / 256)   // 196

typedef unsigned int u32;
typedef unsigned short u16;
typedef __attribute__((ext_vector_type(8))) unsigned short u16x8;
typedef __attribute__((ext_vector_type(8))) __bf16 bf16x8;
typedef __attribute__((ext_vector_type(4))) float f32x4;

// ---------------- bf16 helpers ----------------
__device__ __forceinline__ u32 bf_rne(float f) {
  u32 u = __float_as_uint(f);
  return (u + 0x7FFFu + ((u >> 16) & 1u)) >> 16;
}
__device__ __forceinline__ u32 pack_bf2(float lo, float hi) {
  return bf_rne(lo) | (bf_rne(hi) << 16);
}
__device__ __forceinline__ float bflo(u32 v) { return __uint_as_float(v << 16); }
__device__ __forceinline__ float bfhi(u32 v) { return __uint_as_float(v & 0xFFFF0000u); }

// ---------------- scan helpers ----------------
__device__ __forceinline__ int wave_scan_incl(int v) {
  int lane = threadIdx.x & 63;
#pragma unroll
  for (int d = 1; d < 64; d <<= 1) {
    int u = __shfl_up(v, d, 64);
    if (lane >= d) v += u;
  }
  return v;
}

__device__ __forceinline__ int block_scan_incl(int v, int* wsum) {
  int t = threadIdx.x, lane = t & 63, wid = t >> 6;
  int incl = wave_scan_incl(v);
  if (lane == 63) wsum[wid] = incl;
  __syncthreads();
  int add = 0;
#pragma unroll
  for (int w = 0; w < 3; ++w) add += (w < wid) ? wsum[w] : 0;
  return incl + add;
}

// ---------------- CSR build ----------------
__global__ __launch_bounds__(256) void k_zero(float* __restrict__ deg, int* __restrict__ cur) {
  int i = blockIdx.x * 256 + threadIdx.x;
  if (i < NN) { deg[i] = 0.f; cur[i] = 0; }
}

__global__ __launch_bounds__(256) void k_deg_cnt(const int* __restrict__ ei, const float* __restrict__ ew,
                                                 float* __restrict__ deg, int* __restrict__ cnt) {
  int e = blockIdx.x * 256 + threadIdx.x;
  if (e >= NE) return;
  atomicAdd(&deg[ei[e]], ew[e]);
  atomicAdd(&cnt[ei[NE + e]], 1);
}

__global__ __launch_bounds__(256) void k_dis(const float* __restrict__ deg, float* __restrict__ dis) {
  int i = blockIdx.x * 256 + threadIdx.x;
  if (i < NN) { float d = deg[i]; dis[i] = (d > 0.f) ? rsqrtf(d) : 0.f; }
}

__global__ __launch_bounds__(256) void k_scan1(const int* __restrict__ cnt, int* __restrict__ partials) {
  __shared__ int wsum[4];
  int i = blockIdx.x * 256 + threadIdx.x;
  int v = (i < NN) ? cnt[i] : 0;
  int incl = block_scan_incl(v, wsum);
  if (threadIdx.x == 255) partials[blockIdx.x] = incl;
}

__global__ __launch_bounds__(256) void k_scan2(int* __restrict__ partials, int* __restrict__ rp_last) {
  __shared__ int wsum[4];
  int t = threadIdx.x;
  int v = (t < NBLK) ? partials[t] : 0;
  int incl = block_scan_incl(v, wsum);
  if (t < NBLK) partials[t] = incl - v;     // exclusive block offset
  if (t == 255) rp_last[0] = incl;          // total == NE
}

__global__ __launch_bounds__(256) void k_scan3(int* __restrict__ cnt_cur, const int* __restrict__ partials,
                                               int* __restrict__ rp) {
  __shared__ int wsum[4];
  int i = blockIdx.x * 256 + threadIdx.x;
  int v = (i < NN) ? cnt_cur[i] : 0;
  int incl = block_scan_incl(v, wsum);
  int excl = incl - v + partials[blockIdx.x];
  if (i < NN) { rp[i] = excl; cnt_cur[i] = excl; }  // cnt_cur becomes insert cursor
}

__global__ __launch_bounds__(256) void k_fill(const int* __restrict__ ei, const float* __restrict__ ew,
                                              const float* __restrict__ dis, int* __restrict__ cur,
                                              int* __restrict__ src, float* __restrict__ wv) {
  int e = blockIdx.x * 256 + threadIdx.x;
  if (e >= NE) return;
  int r = ei[e], c = ei[NE + e];
  float w = dis[r] * ew[e] * dis[c];
  int p = atomicAdd(&cur[c], 1);
  src[p] = r;
  wv[p] = w;
}

// ---------------- conversions ----------------
__global__ __launch_bounds__(256) void k_x2bf(const float* __restrict__ x, u32* __restrict__ xb) {
  int i = blockIdx.x * 256 + threadIdx.x;     // pairs
  if (i >= NN * CH / 2) return;
  float2 f = ((const float2*)x)[i];
  xb[i] = pack_bf2(f.x, f.y);
}

// Pack 10 weight matrices into MFMA B-fragment layout:
// frag (m, kb[0..3], cb[0..7]) of 64 lanes x 8 bf16; lane -> col=cb*16+(lane&15),
// k = kb*32 + (lane>>4)*8 + e
__global__ __launch_bounds__(256) void k_wpack(const float* __restrict__ W0, const float* __restrict__ W1,
                                               const float* __restrict__ W2, const float* __restrict__ W3,
                                               u16* __restrict__ Wp) {
  int t = blockIdx.x * 256 + threadIdx.x;
  if (t >= 10 * 4 * 8 * 64) return;
  int lane = t & 63, cb = (t >> 6) & 7, kb = (t >> 9) & 3, m = t >> 11;
  const float* Wb; int io;
  if (m == 0)      { Wb = W0; io = 0; }
  else if (m < 3)  { Wb = W1; io = m - 1; }
  else if (m < 6)  { Wb = W2; io = m - 3; }
  else             { Wb = W3; io = m - 6; }
  const float* s = Wb + (size_t)io * CH * CH;
  int c  = cb * 16 + (lane & 15);
  int k0 = kb * 32 + (lane >> 4) * 8;
  u16* o = Wp + (size_t)t * 8;
#pragma unroll
  for (int e = 0; e < 8; ++e) o[e] = (u16)bf_rne(s[(k0 + e) * CH + c]);
}

// ---------------- propagation (gather, bf16) ----------------
// outb[node] = coefP * sum_j wv[j]*h[src[j]] + coefO*other[node]   (per channel)
// one wave per node; lane handles channels 2*lane, 2*lane+1 (one u32)
__global__ __launch_bounds__(256) void k_prop_bf(const int* __restrict__ rp, const int* __restrict__ src,
                                                 const float* __restrict__ wv, const u32* __restrict__ h,
                                                 const u32* __restrict__ other, u32* __restrict__ outb,
                                                 const float coefP, const float coefO) {
  const int node = blockIdx.x * 4 + (threadIdx.x >> 6);
  const int lane = threadIdx.x & 63;
  if (node >= NN) return;
  const int j0 = rp[node], j1 = rp[node + 1];
  float a0 = 0.f, a1 = 0.f;
  int j = j0;
  for (; j + 4 <= j1; j += 4) {
    int s0 = src[j], s1 = src[j + 1], s2 = src[j + 2], s3 = src[j + 3];
    float w0 = wv[j], w1 = wv[j + 1], w2 = wv[j + 2], w3 = wv[j + 3];
    u32 v0 = h[(size_t)s0 * 64 + lane];
    u32 v1 = h[(size_t)s1 * 64 + lane];
    u32 v2 = h[(size_t)s2 * 64 + lane];
    u32 v3 = h[(size_t)s3 * 64 + lane];
    a0 = fmaf(w0, bflo(v0), a0); a1 = fmaf(w0, bfhi(v0), a1);
    a0 = fmaf(w1, bflo(v1), a0); a1 = fmaf(w1, bfhi(v1), a1);
    a0 = fmaf(w2, bflo(v2), a0); a1 = fmaf(w2, bfhi(v2), a1);
    a0 = fmaf(w3, bflo(v3), a0); a1 = fmaf(w3, bfhi(v3), a1);
  }
  for (; j < j1; ++j) {
    int s = src[j]; float w = wv[j];
    u32 v = h[(size_t)s * 64 + lane];
    a0 = fmaf(w, bflo(v), a0); a1 = fmaf(w, bfhi(v), a1);
  }
  float o0 = 0.f, o1 = 0.f;
  if (other != nullptr) {
    u32 ov = other[(size_t)node * 64 + lane];
    o0 = bfhi(ov); o1 = bfhi(ov);             // placeholder, fixed below
    o0 = bflo(ov); o1 = bfhi(ov);
  }
  float r0 = fmaf(coefP, a0, coefO * o0);
  float r1 = fmaf(coefP, a1, coefO * o1);
  outb[(size_t)node * 64 + lane] = pack_bf2(r0, r1);
}

// ---------------- fused 4-output MFMA GEMM ----------------
// out_k = relu( sum_{i<=k} Tx_i * W_k[i] + b_k ),  k = 0..3
// block: 256 threads (4 waves), 64 output rows; wave w covers cols w*32..w*32+31
__global__ __launch_bounds__(256) void k_gemm_all(
    const u16* __restrict__ xb, const u16* __restrict__ t1,
    const u16* __restrict__ t2, const u16* __restrict__ t3,
    const u16* __restrict__ Wp,
    const float* __restrict__ b0, const float* __restrict__ b1,
    const float* __restrict__ b2, const float* __restrict__ b3,
    float* __restrict__ out) {
  __shared__ __align__(16) char ldsb[4 * 64 * 256];  // 64 KB: 4 bases x 64 rows x 256 B
  const int tid = threadIdx.x;
  const int w = tid >> 6, lane = tid & 63;
  const int rowg0 = blockIdx.x * 64;
  const bool full = (rowg0 + 64 <= NN);
  const u16* bases[4] = {xb, t1, t2, t3};

  // stage 4 basis tiles, XOR-swizzled (row-major D=128 is a 16-way conflict otherwise)
#pragma unroll
  for (int ti = 0; ti < 4; ++ti) {
    const char* src = (const char*)bases[ti];
#pragma unroll
    for (int it = 0; it < 4; ++it) {
      int lin = it * 256 + tid;          // 0..1023
      int row = lin >> 4;                // 0..63
      int seg = (lin & 15) << 4;         // byte 0..240
      int dst = ti * 16384 + row * 256 + (seg ^ ((row & 7) << 4));
      u16x8 v = {0, 0, 0, 0, 0, 0, 0, 0};
      if (full || rowg0 + row < NN)
        v = *(const u16x8*)(src + (size_t)(rowg0 + row) * 256 + seg);
      *(u16x8*)(ldsb + dst) = v;
    }
  }
  __syncthreads();

  const int mbase[4] = {0, 1, 3, 6};
  const float* biases[4] = {b0, b1, b2, b3};
  const int colb = w * 32;

#pragma unroll
  for (int k = 0; k < 4; ++k) {
    f32x4 acc[4][2];
#pragma unroll
    for (int rf = 0; rf < 4; ++rf) {
      acc[rf][0] = (f32x4){0.f, 0.f, 0.f, 0.f};
      acc[rf][1] = (f32x4){0.f, 0.f, 0.f, 0.f};
    }
#pragma unroll
    for (int i = 0; i <= k; ++i) {
      const int m = mbase[k] + i;
      const char* tile = ldsb + i * 16384;
#pragma unroll
      for (int ks = 0; ks < 4; ++ks) {
        const bf16x8 bf0 = __builtin_bit_cast(bf16x8,
            *(const u16x8*)(Wp + (size_t)((m * 4 + ks) * 8 + (w * 2 + 0)) * 512 + lane * 8));
        const bf16x8 bf1 = __builtin_bit_cast(bf16x8,
            *(const u16x8*)(Wp + (size_t)((m * 4 + ks) * 8 + (w * 2 + 1)) * 512 + lane * 8));
#pragma unroll
        for (int rf = 0; rf < 4; ++rf) {
          int row = rf * 16 + (lane & 15);
          int kb = ks * 64 + ((lane >> 4) << 4);
          bf16x8 a = __builtin_bit_cast(bf16x8,
              *(const u16x8*)(tile + row * 256 + (kb ^ ((row & 7) << 4))));
          acc[rf][0] = __builtin_amdgcn_mfma_f32_16x16x32_bf16(a, bf0, acc[rf][0], 0, 0, 0);
          acc[rf][1] = __builtin_amdgcn_mfma_f32_16x16x32_bf16(a, bf1, acc[rf][1], 0, 0, 0);
        }
      }
    }
    // epilogue: bias + relu + fp32 store.  C/D: col=lane&15, row=(lane>>4)*4+j
    const float* bias = biases[k];
    const float bv0 = bias[colb + (lane & 15)];
    const float bv1 = bias[colb + 16 + (lane & 15)];
    float* ok = out + (size_t)k * NN * CH;
#pragma unroll
    for (int rf = 0; rf < 4; ++rf) {
#pragma unroll
      for (int j = 0; j < 4; ++j) {
        int row = rowg0 + rf * 16 + ((lane >> 4) << 2) + j;
        if (row < NN) {
          float v0 = fmaxf(acc[rf][0][j] + bv0, 0.f);
          float v1 = fmaxf(acc[rf][1][j] + bv1, 0.f);
          ok[(size_t)row * CH + colb + (lane & 15)] = v0;
          ok[(size_t)row * CH + colb + 16 + (lane & 15)] = v1;
        }
      }
    }
  }
}

// ---------------- launch ----------------
static inline size_t align256(size_t x) { return (x + 255) & ~(size_t)255; }

extern "C" void kernel_launch(void* const* d_in, const int* in_sizes, int n_in,
                              void* d_out, int out_size, void* d_ws, size_t ws_size,
                              hipStream_t stream) {
  const float* x  = (const float*)d_in[0];
  const int*   ei = (const int*)d_in[1];
  const float* ew = (const float*)d_in[2];
  const float* W[4]  = {(const float*)d_in[3], (const float*)d_in[5],
                        (const float*)d_in[7], (const float*)d_in[9]};
  const float* bs[4] = {(const float*)d_in[4], (const float*)d_in[6],
                        (const float*)d_in[8], (const float*)d_in[10]};
  float* out = (float*)d_out;

  char* ws = (char*)d_ws;
  size_t off = 0;
  auto alloc = [&](size_t bytes) -> void* { void* p = ws + off; off = align256(off + bytes); return p; };
  float* deg      = (float*)alloc(sizeof(float) * NN);
  float* dis      = (float*)alloc(sizeof(float) * NN);
  int*   rp       = (int*)alloc(sizeof(int) * (NN + 1));
  int*   cur      = (int*)alloc(sizeof(int) * NN);
  int*   partials = (int*)alloc(sizeof(int) * 256);
  int*   srcv     = (int*)alloc(sizeof(int) * NE);
  float* wvv      = (float*)alloc(sizeof(float) * NE);
  u32*   xb       = (u32*)alloc(sizeof(u32) * (size_t)NN * 64);
  u32*   t1b      = (u32*)alloc(sizeof(u32) * (size_t)NN * 64);
  u32*   t2b      = (u32*)alloc(sizeof(u32) * (size_t)NN * 64);
  u32*   t3b      = (u32*)alloc(sizeof(u32) * (size_t)NN * 64);
  u16*   Wp       = (u16*)alloc(sizeof(u16) * 10 * 4 * 8 * 64 * 8);
  (void)ws_size; (void)in_sizes; (void)n_in; (void)out_size;

  const int bE = (NE + 255) / 256;
  const int bN = NBLK;

  // CSR build
  k_zero<<<bN, 256, 0, stream>>>(deg, cur);
  k_deg_cnt<<<bE, 256, 0, stream>>>(ei, ew, deg, cur);
  k_dis<<<bN, 256, 0, stream>>>(deg, dis);
  k_scan1<<<bN, 256, 0, stream>>>(cur, partials);
  k_scan2<<<1, 256, 0, stream>>>(partials, rp + NN);
  k_scan3<<<bN, 256, 0, stream>>>(cur, partials, rp);
  k_fill<<<bE, 256, 0, stream>>>(ei, ew, dis, cur, srcv, wvv);

  // conversions
  k_x2bf<<<(NN * CH / 2 + 255) / 256, 256, 0, stream>>>(x, xb);
  k_wpack<<<80, 256, 0, stream>>>(W[0], W[1], W[2], W[3], Wp);

  // basis: Tx1 = -P(x); Tx2 = -1.5 P(Tx1) - 0.5 x; Tx3 = -(5/3) P(Tx2) - (2/3) Tx1
  k_prop_bf<<<12500, 256, 0, stream>>>(rp, srcv, wvv, xb, nullptr, t1b, -1.f, 0.f);
  k_prop_bf<<<12500, 256, 0, stream>>>(rp, srcv, wvv, t1b, xb, t2b, -1.5f, -0.5f);
  k_prop_bf<<<12500, 256, 0, stream>>>(rp, srcv, wvv, t2b, t1b, t3b, -5.f / 3.f, -2.f / 3.f);

  // fused 4-output GEMM with bias+relu
  k_gemm_all<<<(NN + 63) / 64, 256, 0, stream>>>(
      (const u16*)xb, (const u16*)t1b, (const u16*)t2b, (const u16*)t3b,
      Wp, bs[0], bs[1], bs[2], bs[3], out);
}

// Round 3
// 267.703 us; speedup vs baseline: 2.3207x; 1.1823x over previous
//
#include <hip/hip_runtime.h>
#include <cstddef>
#include <cstdint>

#define NN 50000
#define NE 800000
#define CH 128
#define NBLK ((NN + 255) / 256)   // 196

// counting-sort geometry
#define NBUCK 782                 // ceil(50000/64) buckets of 64 cols
#define BH 200                    // blocks in hist/place kernels
#define EPB 4000                  // edges per block (200*4000 = 800000)
#define MH (NBUCK * BH)           // 156400 hist entries
#define G1 ((MH + 255) / 256)     // 611 scan blocks

typedef unsigned int u32;
typedef unsigned short u16;
typedef unsigned long long u64;
typedef __attribute__((ext_vector_type(8))) unsigned short u16x8;
typedef __attribute__((ext_vector_type(8))) __bf16 bf16x8;
typedef __attribute__((ext_vector_type(4))) float f32x4;

// ---------------- bf16 helpers ----------------
__device__ __forceinline__ u32 bf_rne(float f) {
  u32 u = __float_as_uint(f);
  return (u + 0x7FFFu + ((u >> 16) & 1u)) >> 16;
}
__device__ __forceinline__ u32 pack_bf2(float lo, float hi) {
  return bf_rne(lo) | (bf_rne(hi) << 16);
}
__device__ __forceinline__ float bflo(u32 v) { return __uint_as_float(v << 16); }
__device__ __forceinline__ float bfhi(u32 v) { return __uint_as_float(v & 0xFFFF0000u); }

// ---------------- scan helpers ----------------
__device__ __forceinline__ int wave_scan_incl(int v) {
  int lane = threadIdx.x & 63;
#pragma unroll
  for (int d = 1; d < 64; d <<= 1) {
    int u = __shfl_up(v, d, 64);
    if (lane >= d) v += u;
  }
  return v;
}

__device__ __forceinline__ int block_scan_incl(int v, int* wsum) {
  int t = threadIdx.x, lane = t & 63, wid = t >> 6;
  int incl = wave_scan_incl(v);
  if (lane == 63) wsum[wid] = incl;
  __syncthreads();
  int add = 0;
#pragma unroll
  for (int w = 0; w < 3; ++w) add += (w < wid) ? wsum[w] : 0;
  return incl + add;
}

// ---------------- CSR build (counting sort, low-atomic) ----------------
__global__ __launch_bounds__(256) void k_zero(float* __restrict__ deg) {
  int i = blockIdx.x * 256 + threadIdx.x;
  if (i < NN) deg[i] = 0.f;
}

// deg (global float atomics, rows) + coarse col histogram (LDS, no global atomics)
__global__ __launch_bounds__(256) void kA(const int* __restrict__ ei, const float* __restrict__ ew,
                                          float* __restrict__ deg, int* __restrict__ hist) {
  __shared__ int h[NBUCK];
  const int b = blockIdx.x, t = threadIdx.x;
  for (int i = t; i < NBUCK; i += 256) h[i] = 0;
  __syncthreads();
  const int e0 = b * EPB, e1 = (e0 + EPB < NE) ? e0 + EPB : NE;
  for (int e = e0 + t; e < e1; e += 256) {
    atomicAdd(&deg[ei[e]], ew[e]);
    atomicAdd(&h[ei[NE + e] >> 6], 1);
  }
  __syncthreads();
  for (int i = t; i < NBUCK; i += 256) hist[i * BH + b] = h[i];
}

__global__ __launch_bounds__(256) void k_dis(const float* __restrict__ deg, float* __restrict__ dis) {
  int i = blockIdx.x * 256 + threadIdx.x;
  if (i < NN) { float d = deg[i]; dis[i] = (d > 0.f) ? rsqrtf(d) : 0.f; }
}

__global__ __launch_bounds__(256) void k_scan1(const int* __restrict__ hist, int* __restrict__ partials) {
  __shared__ int wsum[4];
  int i = blockIdx.x * 256 + threadIdx.x;
  int v = (i < MH) ? hist[i] : 0;
  int incl = block_scan_incl(v, wsum);
  if (threadIdx.x == 255) partials[blockIdx.x] = incl;
}

__global__ __launch_bounds__(256) void k_scan2(int* __restrict__ partials) {
  __shared__ int wsum[4];
  __shared__ int carrys;
  const int t = threadIdx.x;
  int carry = 0;
#pragma unroll
  for (int r = 0; r < 3; ++r) {
    int idx = r * 256 + t;
    int v = (idx < G1) ? partials[idx] : 0;
    int incl = block_scan_incl(v, wsum);
    if (idx < G1) partials[idx] = carry + incl - v;   // exclusive
    if (t == 255) carrys = incl;
    __syncthreads();
    carry += carrys;
    __syncthreads();
  }
}

__global__ __launch_bounds__(256) void k_scan3(int* __restrict__ hist, const int* __restrict__ partials) {
  __shared__ int wsum[4];
  int i = blockIdx.x * 256 + threadIdx.x;
  int v = (i < MH) ? hist[i] : 0;
  int incl = block_scan_incl(v, wsum);
  if (i < MH) hist[i] = incl - v + partials[blockIdx.x];   // exclusive, in place
}

// place edges into coarse-bucket regions: rank via LDS atomics, plain u64 scatter
__global__ __launch_bounds__(256) void kC(const int* __restrict__ ei, const float* __restrict__ ew,
                                          const int* __restrict__ excl, u64* __restrict__ sorted) {
  __shared__ int lbase[NBUCK];
  __shared__ int lcnt[NBUCK];
  const int b = blockIdx.x, t = threadIdx.x;
  for (int i = t; i < NBUCK; i += 256) { lbase[i] = excl[i * BH + b]; lcnt[i] = 0; }
  __syncthreads();
  const int e0 = b * EPB, e1 = (e0 + EPB < NE) ? e0 + EPB : NE;
  for (int e = e0 + t; e < e1; e += 256) {
    int src = ei[e];
    int col = ei[NE + e];
    u32 ewb = __float_as_uint(ew[e]);
    int bucket = col >> 6;
    int r = atomicAdd(&lcnt[bucket], 1);
    int pos = lbase[bucket] + r;
    sorted[pos] = ((u64)ewb << 32) | (u32)(col << 16) | (u32)src;
  }
}

// exact per-bucket counting sort -> CSR (rp, u16 src, fully-normalized w)
__global__ __launch_bounds__(256) void kD(const u64* __restrict__ sorted, const int* __restrict__ excl,
                                          const float* __restrict__ dis, int* __restrict__ rp,
                                          u16* __restrict__ srcv, float* __restrict__ wvv) {
  __shared__ int h[64];
  __shared__ int cur[64];
  __shared__ float disc[64];
  const int b = blockIdx.x, t = threadIdx.x;
  const int seg0 = excl[b * BH];
  const int seg1 = (b + 1 < NBUCK) ? excl[(b + 1) * BH] : NE;
  if (t < 64) {
    h[t] = 0;
    int c = (b << 6) + t;
    disc[t] = (c < NN) ? dis[c] : 0.f;
  }
  __syncthreads();
  for (int p = seg0 + t; p < seg1; p += 256) {
    u32 lo = (u32)sorted[p];
    atomicAdd(&h[(lo >> 16) & 63], 1);
  }
  __syncthreads();
  if (t < 64) {
    int v = h[t];
    int incl = wave_scan_incl(v);
    int excl_l = incl - v;
    cur[t] = seg0 + excl_l;
    int c = (b << 6) + t;
    if (c < NN) rp[c] = seg0 + excl_l;
    else if (c == NN) rp[NN] = seg0 + excl_l;   // == NE (no edges at cols >= NN)
  }
  __syncthreads();
  for (int p = seg0 + t; p < seg1; p += 256) {
    u64 v = sorted[p];
    u32 lo = (u32)v;
    int src = lo & 0xFFFF;
    int local = (lo >> 16) & 63;
    float ewf = __uint_as_float((u32)(v >> 32));
    int q = atomicAdd(&cur[local], 1);
    srcv[q] = (u16)src;
    wvv[q] = ewf * dis[src] * disc[local];
  }
}

// ---------------- conversions ----------------
__global__ __launch_bounds__(256) void k_x2bf(const float* __restrict__ x, u32* __restrict__ xb) {
  int i = blockIdx.x * 256 + threadIdx.x;     // pairs
  if (i >= NN * CH / 2) return;
  float2 f = ((const float2*)x)[i];
  xb[i] = pack_bf2(f.x, f.y);
}

// Pack 10 weight matrices into MFMA B-fragment layout (see round-2 comment)
__global__ __launch_bounds__(256) void k_wpack(const float* __restrict__ W0, const float* __restrict__ W1,
                                               const float* __restrict__ W2, const float* __restrict__ W3,
                                               u16* __restrict__ Wp) {
  int t = blockIdx.x * 256 + threadIdx.x;
  if (t >= 10 * 4 * 8 * 64) return;
  int lane = t & 63, cb = (t >> 6) & 7, kb = (t >> 9) & 3, m = t >> 11;
  const float* Wb; int io;
  if (m == 0)      { Wb = W0; io = 0; }
  else if (m < 3)  { Wb = W1; io = m - 1; }
  else if (m < 6)  { Wb = W2; io = m - 3; }
  else             { Wb = W3; io = m - 6; }
  const float* s = Wb + (size_t)io * CH * CH;
  int c  = cb * 16 + (lane & 15);
  int k0 = kb * 32 + (lane >> 4) * 8;
  u16* o = Wp + (size_t)t * 8;
#pragma unroll
  for (int e = 0; e < 8; ++e) o[e] = (u16)bf_rne(s[(k0 + e) * CH + c]);
}

// ---------------- propagation (gather, bf16) ----------------
__global__ __launch_bounds__(256) void k_prop_bf(const int* __restrict__ rp, const u16* __restrict__ src,
                                                 const float* __restrict__ wv, const u32* __restrict__ h,
                                                 const u32* __restrict__ other, u32* __restrict__ outb,
                                                 const float coefP, const float coefO) {
  const int node = blockIdx.x * 4 + (threadIdx.x >> 6);
  const int lane = threadIdx.x & 63;
  if (node >= NN) return;
  const int j0 = rp[node], j1 = rp[node + 1];
  float a0 = 0.f, a1 = 0.f;
  int j = j0;
  for (; j + 4 <= j1; j += 4) {
    int s0 = src[j], s1 = src[j + 1], s2 = src[j + 2], s3 = src[j + 3];
    float w0 = wv[j], w1 = wv[j + 1], w2 = wv[j + 2], w3 = wv[j + 3];
    u32 v0 = h[(size_t)s0 * 64 + lane];
    u32 v1 = h[(size_t)s1 * 64 + lane];
    u32 v2 = h[(size_t)s2 * 64 + lane];
    u32 v3 = h[(size_t)s3 * 64 + lane];
    a0 = fmaf(w0, bflo(v0), a0); a1 = fmaf(w0, bfhi(v0), a1);
    a0 = fmaf(w1, bflo(v1), a0); a1 = fmaf(w1, bfhi(v1), a1);
    a0 = fmaf(w2, bflo(v2), a0); a1 = fmaf(w2, bfhi(v2), a1);
    a0 = fmaf(w3, bflo(v3), a0); a1 = fmaf(w3, bfhi(v3), a1);
  }
  for (; j < j1; ++j) {
    int s = src[j]; float w = wv[j];
    u32 v = h[(size_t)s * 64 + lane];
    a0 = fmaf(w, bflo(v), a0); a1 = fmaf(w, bfhi(v), a1);
  }
  float o0 = 0.f, o1 = 0.f;
  if (other != nullptr) {
    u32 ov = other[(size_t)node * 64 + lane];
    o0 = bflo(ov); o1 = bfhi(ov);
  }
  float r0 = fmaf(coefP, a0, coefO * o0);
  float r1 = fmaf(coefP, a1, coefO * o1);
  outb[(size_t)node * 64 + lane] = pack_bf2(r0, r1);
}

// ---------------- fused 4-output MFMA GEMM ----------------
__global__ __launch_bounds__(256) void k_gemm_all(
    const u16* __restrict__ xb, const u16* __restrict__ t1,
    const u16* __restrict__ t2, const u16* __restrict__ t3,
    const u16* __restrict__ Wp,
    const float* __restrict__ b0, const float* __restrict__ b1,
    const float* __restrict__ b2, const float* __restrict__ b3,
    float* __restrict__ out) {
  __shared__ __align__(16) char ldsb[4 * 64 * 256];  // 64 KB
  const int tid = threadIdx.x;
  const int w = tid >> 6, lane = tid & 63;
  const int rowg0 = blockIdx.x * 64;
  const bool full = (rowg0 + 64 <= NN);
  const u16* bases[4] = {xb, t1, t2, t3};

#pragma unroll
  for (int ti = 0; ti < 4; ++ti) {
    const char* src = (const char*)bases[ti];
#pragma unroll
    for (int it = 0; it < 4; ++it) {
      int lin = it * 256 + tid;          // 0..1023
      int row = lin >> 4;                // 0..63
      int seg = (lin & 15) << 4;         // byte 0..240
      int dst = ti * 16384 + row * 256 + (seg ^ ((row & 7) << 4));
      u16x8 v = {0, 0, 0, 0, 0, 0, 0, 0};
      if (full || rowg0 + row < NN)
        v = *(const u16x8*)(src + (size_t)(rowg0 + row) * 256 + seg);
      *(u16x8*)(ldsb + dst) = v;
    }
  }
  __syncthreads();

  const int mbase[4] = {0, 1, 3, 6};
  const float* biases[4] = {b0, b1, b2, b3};
  const int colb = w * 32;

#pragma unroll
  for (int k = 0; k < 4; ++k) {
    f32x4 acc[4][2];
#pragma unroll
    for (int rf = 0; rf < 4; ++rf) {
      acc[rf][0] = (f32x4){0.f, 0.f, 0.f, 0.f};
      acc[rf][1] = (f32x4){0.f, 0.f, 0.f, 0.f};
    }
#pragma unroll
    for (int i = 0; i <= k; ++i) {
      const int m = mbase[k] + i;
      const char* tile = ldsb + i * 16384;
#pragma unroll
      for (int ks = 0; ks < 4; ++ks) {
        const bf16x8 bf0 = __builtin_bit_cast(bf16x8,
            *(const u16x8*)(Wp + (size_t)((m * 4 + ks) * 8 + (w * 2 + 0)) * 512 + lane * 8));
        const bf16x8 bf1 = __builtin_bit_cast(bf16x8,
            *(const u16x8*)(Wp + (size_t)((m * 4 + ks) * 8 + (w * 2 + 1)) * 512 + lane * 8));
#pragma unroll
        for (int rf = 0; rf < 4; ++rf) {
          int row = rf * 16 + (lane & 15);
          int kb = ks * 64 + ((lane >> 4) << 4);
          bf16x8 a = __builtin_bit_cast(bf16x8,
              *(const u16x8*)(tile + row * 256 + (kb ^ ((row & 7) << 4))));
          acc[rf][0] = __builtin_amdgcn_mfma_f32_16x16x32_bf16(a, bf0, acc[rf][0], 0, 0, 0);
          acc[rf][1] = __builtin_amdgcn_mfma_f32_16x16x32_bf16(a, bf1, acc[rf][1], 0, 0, 0);
        }
      }
    }
    const float* bias = biases[k];
    const float bv0 = bias[colb + (lane & 15)];
    const float bv1 = bias[colb + 16 + (lane & 15)];
    float* ok = out + (size_t)k * NN * CH;
#pragma unroll
    for (int rf = 0; rf < 4; ++rf) {
#pragma unroll
      for (int j = 0; j < 4; ++j) {
        int row = rowg0 + rf * 16 + ((lane >> 4) << 2) + j;
        if (row < NN) {
          float v0 = fmaxf(acc[rf][0][j] + bv0, 0.f);
          float v1 = fmaxf(acc[rf][1][j] + bv1, 0.f);
          ok[(size_t)row * CH + colb + (lane & 15)] = v0;
          ok[(size_t)row * CH + colb + 16 + (lane & 15)] = v1;
        }
      }
    }
  }
}

// ---------------- launch ----------------
static inline size_t align256(size_t x) { return (x + 255) & ~(size_t)255; }

extern "C" void kernel_launch(void* const* d_in, const int* in_sizes, int n_in,
                              void* d_out, int out_size, void* d_ws, size_t ws_size,
                              hipStream_t stream) {
  const float* x  = (const float*)d_in[0];
  const int*   ei = (const int*)d_in[1];
  const float* ew = (const float*)d_in[2];
  const float* W[4]  = {(const float*)d_in[3], (const float*)d_in[5],
                        (const float*)d_in[7], (const float*)d_in[9]};
  const float* bs[4] = {(const float*)d_in[4], (const float*)d_in[6],
                        (const float*)d_in[8], (const float*)d_in[10]};
  float* out = (float*)d_out;

  char* ws = (char*)d_ws;
  size_t off = 0;
  auto alloc = [&](size_t bytes) -> void* { void* p = ws + off; off = align256(off + bytes); return p; };
  float* deg      = (float*)alloc(sizeof(float) * NN);
  float* dis      = (float*)alloc(sizeof(float) * NN);
  int*   rp       = (int*)alloc(sizeof(int) * (NN + 1));
  int*   hist     = (int*)alloc(sizeof(int) * MH);
  int*   partials = (int*)alloc(sizeof(int) * 1024);
  u64*   sorted   = (u64*)alloc(sizeof(u64) * NE);
  u16*   srcv     = (u16*)alloc(sizeof(u16) * NE);
  float* wvv      = (float*)alloc(sizeof(float) * NE);
  u32*   xb       = (u32*)alloc(sizeof(u32) * (size_t)NN * 64);
  u32*   t1b      = (u32*)alloc(sizeof(u32) * (size_t)NN * 64);
  u32*   t2b      = (u32*)alloc(sizeof(u32) * (size_t)NN * 64);
  u32*   t3b      = (u32*)alloc(sizeof(u32) * (size_t)NN * 64);
  u16*   Wp       = (u16*)alloc(sizeof(u16) * 10 * 4 * 8 * 64 * 8);
  (void)ws_size; (void)in_sizes; (void)n_in; (void)out_size;

  // CSR build (counting sort)
  k_zero<<<NBLK, 256, 0, stream>>>(deg);
  kA<<<BH, 256, 0, stream>>>(ei, ew, deg, hist);
  k_dis<<<NBLK, 256, 0, stream>>>(deg, dis);
  k_scan1<<<G1, 256, 0, stream>>>(hist, partials);
  k_scan2<<<1, 256, 0, stream>>>(partials);
  k_scan3<<<G1, 256, 0, stream>>>(hist, partials);
  kC<<<BH, 256, 0, stream>>>(ei, ew, hist, sorted);
  kD<<<NBUCK, 256, 0, stream>>>(sorted, hist, dis, rp, srcv, wvv);

  // conversions
  k_x2bf<<<(NN * CH / 2 + 255) / 256, 256, 0, stream>>>(x, xb);
  k_wpack<<<80, 256, 0, stream>>>(W[0], W[1], W[2], W[3], Wp);

  // basis: Tx1 = -P(x); Tx2 = -1.5 P(Tx1) - 0.5 x; Tx3 = -(5/3) P(Tx2) - (2/3) Tx1
  k_prop_bf<<<12500, 256, 0, stream>>>(rp, srcv, wvv, xb, nullptr, t1b, -1.f, 0.f);
  k_prop_bf<<<12500, 256, 0, stream>>>(rp, srcv, wvv, t1b, xb, t2b, -1.5f, -0.5f);
  k_prop_bf<<<12500, 256, 0, stream>>>(rp, srcv, wvv, t2b, t1b, t3b, -5.f / 3.f, -2.f / 3.f);

  // fused 4-output GEMM with bias+relu
  k_gemm_all<<<(NN + 63) / 64, 256, 0, stream>>>(
      (const u16*)xb, (const u16*)t1b, (const u16*)t2b, (const u16*)t3b,
      Wp, bs[0], bs[1], bs[2], bs[3], out);
}

// Round 4
// 237.211 us; speedup vs baseline: 2.6190x; 1.1285x over previous
//
#include <hip/hip_runtime.h>
#include <cstddef>
#include <cstdint>

#define NN 50000
#define NE 800000
#define CH 128
#define NBLK ((NN + 255) / 256)   // 196

// counting-sort geometry
#define NBUCK 782                 // ceil(50000/64) buckets of 64 cols
#define BH 200                    // blocks in hist/place kernels
#define EPB 4000                  // edges per block (200*4000 = 800000)
#define MH (NBUCK * BH)           // 156400 hist entries
#define G1 ((MH + 255) / 256)     // 611 scan blocks

typedef unsigned int u32;
typedef unsigned short u16;
typedef unsigned long long u64;
typedef __attribute__((ext_vector_type(8))) unsigned short u16x8;
typedef __attribute__((ext_vector_type(8))) __bf16 bf16x8;
typedef __attribute__((ext_vector_type(4))) float f32x4;

// ---------------- bf16 helpers ----------------
__device__ __forceinline__ u32 bf_rne(float f) {
  u32 u = __float_as_uint(f);
  return (u + 0x7FFFu + ((u >> 16) & 1u)) >> 16;
}
__device__ __forceinline__ u32 pack_bf2(float lo, float hi) {
  return bf_rne(lo) | (bf_rne(hi) << 16);
}
__device__ __forceinline__ float bflo(u32 v) { return __uint_as_float(v << 16); }
__device__ __forceinline__ float bfhi(u32 v) { return __uint_as_float(v & 0xFFFF0000u); }

// ---------------- scan helpers ----------------
__device__ __forceinline__ int wave_scan_incl(int v) {
  int lane = threadIdx.x & 63;
#pragma unroll
  for (int d = 1; d < 64; d <<= 1) {
    int u = __shfl_up(v, d, 64);
    if (lane >= d) v += u;
  }
  return v;
}

__device__ __forceinline__ int block_scan_incl(int v, int* wsum) {
  int t = threadIdx.x, lane = t & 63, wid = t >> 6;
  int incl = wave_scan_incl(v);
  if (lane == 63) wsum[wid] = incl;
  __syncthreads();
  int add = 0;
#pragma unroll
  for (int w = 0; w < 3; ++w) add += (w < wid) ? wsum[w] : 0;
  return incl + add;
}

// ---------------- CSR build (counting sort, low-atomic) ----------------
__global__ __launch_bounds__(256) void k_zero(float* __restrict__ deg) {
  int i = blockIdx.x * 256 + threadIdx.x;
  if (i < NN) deg[i] = 0.f;
}

__global__ __launch_bounds__(256) void kA(const int* __restrict__ ei, const float* __restrict__ ew,
                                          float* __restrict__ deg, int* __restrict__ hist) {
  __shared__ int h[NBUCK];
  const int b = blockIdx.x, t = threadIdx.x;
  for (int i = t; i < NBUCK; i += 256) h[i] = 0;
  __syncthreads();
  const int e0 = b * EPB, e1 = (e0 + EPB < NE) ? e0 + EPB : NE;
  for (int e = e0 + t; e < e1; e += 256) {
    atomicAdd(&deg[ei[e]], ew[e]);
    atomicAdd(&h[ei[NE + e] >> 6], 1);
  }
  __syncthreads();
  for (int i = t; i < NBUCK; i += 256) hist[i * BH + b] = h[i];
}

__global__ __launch_bounds__(256) void k_dis(const float* __restrict__ deg, float* __restrict__ dis) {
  int i = blockIdx.x * 256 + threadIdx.x;
  if (i < NN) { float d = deg[i]; dis[i] = (d > 0.f) ? rsqrtf(d) : 0.f; }
}

__global__ __launch_bounds__(256) void k_scan1(const int* __restrict__ hist, int* __restrict__ partials) {
  __shared__ int wsum[4];
  int i = blockIdx.x * 256 + threadIdx.x;
  int v = (i < MH) ? hist[i] : 0;
  int incl = block_scan_incl(v, wsum);
  if (threadIdx.x == 255) partials[blockIdx.x] = incl;
}

__global__ __launch_bounds__(256) void k_scan2(int* __restrict__ partials) {
  __shared__ int wsum[4];
  __shared__ int carrys;
  const int t = threadIdx.x;
  int carry = 0;
#pragma unroll
  for (int r = 0; r < 3; ++r) {
    int idx = r * 256 + t;
    int v = (idx < G1) ? partials[idx] : 0;
    int incl = block_scan_incl(v, wsum);
    if (idx < G1) partials[idx] = carry + incl - v;   // exclusive
    if (t == 255) carrys = incl;
    __syncthreads();
    carry += carrys;
    __syncthreads();
  }
}

__global__ __launch_bounds__(256) void k_scan3(int* __restrict__ hist, const int* __restrict__ partials) {
  __shared__ int wsum[4];
  int i = blockIdx.x * 256 + threadIdx.x;
  int v = (i < MH) ? hist[i] : 0;
  int incl = block_scan_incl(v, wsum);
  if (i < MH) hist[i] = incl - v + partials[blockIdx.x];   // exclusive, in place
}

__global__ __launch_bounds__(256) void kC(const int* __restrict__ ei, const float* __restrict__ ew,
                                          const int* __restrict__ excl, u64* __restrict__ sorted) {
  __shared__ int lbase[NBUCK];
  __shared__ int lcnt[NBUCK];
  const int b = blockIdx.x, t = threadIdx.x;
  for (int i = t; i < NBUCK; i += 256) { lbase[i] = excl[i * BH + b]; lcnt[i] = 0; }
  __syncthreads();
  const int e0 = b * EPB, e1 = (e0 + EPB < NE) ? e0 + EPB : NE;
  for (int e = e0 + t; e < e1; e += 256) {
    int src = ei[e];
    int col = ei[NE + e];
    u32 ewb = __float_as_uint(ew[e]);
    int bucket = col >> 6;
    int r = atomicAdd(&lcnt[bucket], 1);
    int pos = lbase[bucket] + r;
    sorted[pos] = ((u64)ewb << 32) | (u32)(col << 16) | (u32)src;
  }
}

__global__ __launch_bounds__(256) void kD(const u64* __restrict__ sorted, const int* __restrict__ excl,
                                          const float* __restrict__ dis, int* __restrict__ rp,
                                          u16* __restrict__ srcv, float* __restrict__ wvv) {
  __shared__ int h[64];
  __shared__ int cur[64];
  __shared__ float disc[64];
  const int b = blockIdx.x, t = threadIdx.x;
  const int seg0 = excl[b * BH];
  const int seg1 = (b + 1 < NBUCK) ? excl[(b + 1) * BH] : NE;
  if (t < 64) {
    h[t] = 0;
    int c = (b << 6) + t;
    disc[t] = (c < NN) ? dis[c] : 0.f;
  }
  __syncthreads();
  for (int p = seg0 + t; p < seg1; p += 256) {
    u32 lo = (u32)sorted[p];
    atomicAdd(&h[(lo >> 16) & 63], 1);
  }
  __syncthreads();
  if (t < 64) {
    int v = h[t];
    int incl = wave_scan_incl(v);
    int excl_l = incl - v;
    cur[t] = seg0 + excl_l;
    int c = (b << 6) + t;
    if (c < NN) rp[c] = seg0 + excl_l;
    else if (c == NN) rp[NN] = seg0 + excl_l;   // == NE
  }
  __syncthreads();
  for (int p = seg0 + t; p < seg1; p += 256) {
    u64 v = sorted[p];
    u32 lo = (u32)v;
    int src = lo & 0xFFFF;
    int local = (lo >> 16) & 63;
    float ewf = __uint_as_float((u32)(v >> 32));
    int q = atomicAdd(&cur[local], 1);
    srcv[q] = (u16)src;
    wvv[q] = ewf * dis[src] * disc[local];
  }
}

// ---------------- conversions ----------------
__global__ __launch_bounds__(256) void k_x2bf(const float* __restrict__ x, u32* __restrict__ xb) {
  int i = blockIdx.x * 256 + threadIdx.x;     // pairs
  if (i >= NN * CH / 2) return;
  float2 f = ((const float2*)x)[i];
  xb[i] = pack_bf2(f.x, f.y);
}

// Pack 10 weight matrices into MFMA B-fragment layout
__global__ __launch_bounds__(256) void k_wpack(const float* __restrict__ W0, const float* __restrict__ W1,
                                               const float* __restrict__ W2, const float* __restrict__ W3,
                                               u16* __restrict__ Wp) {
  int t = blockIdx.x * 256 + threadIdx.x;
  if (t >= 10 * 4 * 8 * 64) return;
  int lane = t & 63, cb = (t >> 6) & 7, kb = (t >> 9) & 3, m = t >> 11;
  const float* Wb; int io;
  if (m == 0)      { Wb = W0; io = 0; }
  else if (m < 3)  { Wb = W1; io = m - 1; }
  else if (m < 6)  { Wb = W2; io = m - 3; }
  else             { Wb = W3; io = m - 6; }
  const float* s = Wb + (size_t)io * CH * CH;
  int c  = cb * 16 + (lane & 15);
  int k0 = kb * 32 + (lane >> 4) * 8;
  u16* o = Wp + (size_t)t * 8;
#pragma unroll
  for (int e = 0; e < 8; ++e) o[e] = (u16)bf_rne(s[(k0 + e) * CH + c]);
}

// ---------------- propagation (gather, bf16) ----------------
// coalesced edge-meta load + shfl broadcast (was: 64x redundant uniform loads)
__global__ __launch_bounds__(256) void k_prop_bf(const int* __restrict__ rp, const u16* __restrict__ src,
                                                 const float* __restrict__ wv, const u32* __restrict__ h,
                                                 const u32* __restrict__ other, u32* __restrict__ outb,
                                                 const float coefP, const float coefO) {
  const int node = blockIdx.x * 4 + (threadIdx.x >> 6);
  const int lane = threadIdx.x & 63;
  if (node >= NN) return;
  const int j0 = rp[node], j1 = rp[node + 1];
  float a0 = 0.f, a1 = 0.f;
  for (int base = j0; base < j1; base += 64) {
    int cnt = j1 - base; if (cnt > 64) cnt = 64;
    int s = 0; float wl = 0.f;
    if (lane < cnt) { s = src[base + lane]; wl = wv[base + lane]; }
    int jj = 0;
    for (; jj + 4 <= cnt; jj += 4) {
      int s0 = __shfl(s, jj), s1 = __shfl(s, jj + 1), s2 = __shfl(s, jj + 2), s3 = __shfl(s, jj + 3);
      float w0 = __shfl(wl, jj), w1 = __shfl(wl, jj + 1), w2 = __shfl(wl, jj + 2), w3 = __shfl(wl, jj + 3);
      u32 v0 = h[(size_t)s0 * 64 + lane];
      u32 v1 = h[(size_t)s1 * 64 + lane];
      u32 v2 = h[(size_t)s2 * 64 + lane];
      u32 v3 = h[(size_t)s3 * 64 + lane];
      a0 = fmaf(w0, bflo(v0), a0); a1 = fmaf(w0, bfhi(v0), a1);
      a0 = fmaf(w1, bflo(v1), a0); a1 = fmaf(w1, bfhi(v1), a1);
      a0 = fmaf(w2, bflo(v2), a0); a1 = fmaf(w2, bfhi(v2), a1);
      a0 = fmaf(w3, bflo(v3), a0); a1 = fmaf(w3, bfhi(v3), a1);
    }
    for (; jj < cnt; ++jj) {
      int sj = __shfl(s, jj);
      float wj = __shfl(wl, jj);
      u32 v = h[(size_t)sj * 64 + lane];
      a0 = fmaf(wj, bflo(v), a0); a1 = fmaf(wj, bfhi(v), a1);
    }
  }
  float o0 = 0.f, o1 = 0.f;
  if (other != nullptr) {
    u32 ov = other[(size_t)node * 64 + lane];
    o0 = bflo(ov); o1 = bfhi(ov);
  }
  float r0 = fmaf(coefP, a0, coefO * o0);
  float r1 = fmaf(coefP, a1, coefO * o1);
  outb[(size_t)node * 64 + lane] = pack_bf2(r0, r1);
}

// ---------------- fused 4-output MFMA GEMM (streamed basis tiles) ----------------
// 32 rows/block, 4 waves (wave w -> cols w*32..w*32+31).
// i-outer: stream basis tile i through a double-buffered 8KB LDS stage,
// keep all 4 output accumulators live; each tile read from LDS once.
__global__ __launch_bounds__(256, 4) void k_gemm_all(
    const u16* __restrict__ xb, const u16* __restrict__ t1,
    const u16* __restrict__ t2, const u16* __restrict__ t3,
    const u16* __restrict__ Wp,
    const float* __restrict__ b0, const float* __restrict__ b1,
    const float* __restrict__ b2, const float* __restrict__ b3,
    float* __restrict__ out) {
  __shared__ __align__(16) char ldsb[2][8192];   // 2 x 32 rows x 256 B
  const int tid = threadIdx.x;
  const int w = tid >> 6, lane = tid & 63;
  const int rowg0 = blockIdx.x * 32;
  const u16* bases[4] = {xb, t1, t2, t3};
  const int mbase[4] = {0, 1, 3, 6};

  // chunk coords for this thread's two staging slots
  const int c0 = tid,        r_0 = c0 >> 4, s_0 = (c0 & 15) << 4;
  const int c1 = 256 + tid,  r_1 = c1 >> 4, s_1 = (c1 & 15) << 4;

  f32x4 acc[4][2][2];
#pragma unroll
  for (int k = 0; k < 4; ++k)
#pragma unroll
    for (int rf = 0; rf < 2; ++rf)
#pragma unroll
      for (int c = 0; c < 2; ++c) acc[k][rf][c] = (f32x4){0.f, 0.f, 0.f, 0.f};

  // prologue: stage tile 0
  {
    u16x8 v0 = {0,0,0,0,0,0,0,0}, v1 = {0,0,0,0,0,0,0,0};
    if (rowg0 + r_0 < NN) v0 = *(const u16x8*)((const char*)bases[0] + (size_t)(rowg0 + r_0) * 256 + s_0);
    if (rowg0 + r_1 < NN) v1 = *(const u16x8*)((const char*)bases[0] + (size_t)(rowg0 + r_1) * 256 + s_1);
    *(u16x8*)(&ldsb[0][r_0 * 256 + (s_0 ^ ((r_0 & 7) << 4))]) = v0;
    *(u16x8*)(&ldsb[1][0] - 8192 + 8192) ;  // no-op keep symmetry
    *(u16x8*)(&ldsb[0][r_1 * 256 + (s_1 ^ ((r_1 & 7) << 4))]) = v1;
  }
  __syncthreads();

#pragma unroll
  for (int i = 0; i < 4; ++i) {
    // issue next tile's global loads before compute (latency hides under MFMA)
    u16x8 nv0 = {0,0,0,0,0,0,0,0}, nv1 = {0,0,0,0,0,0,0,0};
    if (i < 3) {
      if (rowg0 + r_0 < NN) nv0 = *(const u16x8*)((const char*)bases[i + 1] + (size_t)(rowg0 + r_0) * 256 + s_0);
      if (rowg0 + r_1 < NN) nv1 = *(const u16x8*)((const char*)bases[i + 1] + (size_t)(rowg0 + r_1) * 256 + s_1);
    }

    const char* tile = ldsb[i & 1];
#pragma unroll
    for (int ks = 0; ks < 4; ++ks) {
      const int kb = ks * 64 + ((lane >> 4) << 4);
      const int r0 = (lane & 15), r1 = 16 + (lane & 15);
      const bf16x8 a0 = __builtin_bit_cast(bf16x8,
          *(const u16x8*)(tile + r0 * 256 + (kb ^ ((r0 & 7) << 4))));
      const bf16x8 a1 = __builtin_bit_cast(bf16x8,
          *(const u16x8*)(tile + r1 * 256 + (kb ^ ((r1 & 7) << 4))));
#pragma unroll
      for (int k = 3; k >= 0; --k) {
        if (k < i) continue;
        const int m = mbase[k] + i;
        const bf16x8 bf0 = __builtin_bit_cast(bf16x8,
            *(const u16x8*)(Wp + (size_t)((m * 4 + ks) * 8 + (w * 2 + 0)) * 512 + lane * 8));
        const bf16x8 bf1 = __builtin_bit_cast(bf16x8,
            *(const u16x8*)(Wp + (size_t)((m * 4 + ks) * 8 + (w * 2 + 1)) * 512 + lane * 8));
        acc[k][0][0] = __builtin_amdgcn_mfma_f32_16x16x32_bf16(a0, bf0, acc[k][0][0], 0, 0, 0);
        acc[k][1][0] = __builtin_amdgcn_mfma_f32_16x16x32_bf16(a1, bf0, acc[k][1][0], 0, 0, 0);
        acc[k][0][1] = __builtin_amdgcn_mfma_f32_16x16x32_bf16(a0, bf1, acc[k][0][1], 0, 0, 0);
        acc[k][1][1] = __builtin_amdgcn_mfma_f32_16x16x32_bf16(a1, bf1, acc[k][1][1], 0, 0, 0);
      }
    }
    if (i < 3) {
      char* nb = ldsb[(i + 1) & 1];
      *(u16x8*)(&nb[r_0 * 256 + (s_0 ^ ((r_0 & 7) << 4))]) = nv0;
      *(u16x8*)(&nb[r_1 * 256 + (s_1 ^ ((r_1 & 7) << 4))]) = nv1;
    }
    __syncthreads();
  }

  // epilogue: bias + relu + fp32 store.  C/D: col=lane&15, row=(lane>>4)*4+j
  const float* biases[4] = {b0, b1, b2, b3};
  const int colb = w * 32;
#pragma unroll
  for (int k = 0; k < 4; ++k) {
    const float bv0 = biases[k][colb + (lane & 15)];
    const float bv1 = biases[k][colb + 16 + (lane & 15)];
    float* ok = out + (size_t)k * NN * CH;
#pragma unroll
    for (int rf = 0; rf < 2; ++rf) {
#pragma unroll
      for (int j = 0; j < 4; ++j) {
        const int row = rowg0 + rf * 16 + ((lane >> 4) << 2) + j;
        if (row < NN) {
          ok[(size_t)row * CH + colb + (lane & 15)]      = fmaxf(acc[k][rf][0][j] + bv0, 0.f);
          ok[(size_t)row * CH + colb + 16 + (lane & 15)] = fmaxf(acc[k][rf][1][j] + bv1, 0.f);
        }
      }
    }
  }
}

// ---------------- launch ----------------
static inline size_t align256(size_t x) { return (x + 255) & ~(size_t)255; }

extern "C" void kernel_launch(void* const* d_in, const int* in_sizes, int n_in,
                              void* d_out, int out_size, void* d_ws, size_t ws_size,
                              hipStream_t stream) {
  const float* x  = (const float*)d_in[0];
  const int*   ei = (const int*)d_in[1];
  const float* ew = (const float*)d_in[2];
  const float* W[4]  = {(const float*)d_in[3], (const float*)d_in[5],
                        (const float*)d_in[7], (const float*)d_in[9]};
  const float* bs[4] = {(const float*)d_in[4], (const float*)d_in[6],
                        (const float*)d_in[8], (const float*)d_in[10]};
  float* out = (float*)d_out;

  char* ws = (char*)d_ws;
  size_t off = 0;
  auto alloc = [&](size_t bytes) -> void* { void* p = ws + off; off = align256(off + bytes); return p; };
  float* deg      = (float*)alloc(sizeof(float) * NN);
  float* dis      = (float*)alloc(sizeof(float) * NN);
  int*   rp       = (int*)alloc(sizeof(int) * (NN + 1));
  int*   hist     = (int*)alloc(sizeof(int) * MH);
  int*   partials = (int*)alloc(sizeof(int) * 1024);
  u64*   sorted   = (u64*)alloc(sizeof(u64) * NE);
  u16*   srcv     = (u16*)alloc(sizeof(u16) * NE);
  float* wvv      = (float*)alloc(sizeof(float) * NE);
  u32*   xb       = (u32*)alloc(sizeof(u32) * (size_t)NN * 64);
  u32*   t1b      = (u32*)alloc(sizeof(u32) * (size_t)NN * 64);
  u32*   t2b      = (u32*)alloc(sizeof(u32) * (size_t)NN * 64);
  u32*   t3b      = (u32*)alloc(sizeof(u32) * (size_t)NN * 64);
  u16*   Wp       = (u16*)alloc(sizeof(u16) * 10 * 4 * 8 * 64 * 8);
  (void)ws_size; (void)in_sizes; (void)n_in; (void)out_size;

  // CSR build (counting sort)
  k_zero<<<NBLK, 256, 0, stream>>>(deg);
  kA<<<BH, 256, 0, stream>>>(ei, ew, deg, hist);
  k_dis<<<NBLK, 256, 0, stream>>>(deg, dis);
  k_scan1<<<G1, 256, 0, stream>>>(hist, partials);
  k_scan2<<<1, 256, 0, stream>>>(partials);
  k_scan3<<<G1, 256, 0, stream>>>(hist, partials);
  kC<<<BH, 256, 0, stream>>>(ei, ew, hist, sorted);
  kD<<<NBUCK, 256, 0, stream>>>(sorted, hist, dis, rp, srcv, wvv);

  // conversions
  k_x2bf<<<(NN * CH / 2 + 255) / 256, 256, 0, stream>>>(x, xb);
  k_wpack<<<80, 256, 0, stream>>>(W[0], W[1], W[2], W[3], Wp);

  // basis: Tx1 = -P(x); Tx2 = -1.5 P(Tx1) - 0.5 x; Tx3 = -(5/3) P(Tx2) - (2/3) Tx1
  k_prop_bf<<<12500, 256, 0, stream>>>(rp, srcv, wvv, xb, nullptr, t1b, -1.f, 0.f);
  k_prop_bf<<<12500, 256, 0, stream>>>(rp, srcv, wvv, t1b, xb, t2b, -1.5f, -0.5f);
  k_prop_bf<<<12500, 256, 0, stream>>>(rp, srcv, wvv, t2b, t1b, t3b, -5.f / 3.f, -2.f / 3.f);

  // fused 4-output GEMM with bias+relu (32-row blocks)
  k_gemm_all<<<(NN + 31) / 32, 256, 0, stream>>>(
      (const u16*)xb, (const u16*)t1b, (const u16*)t2b, (const u16*)t3b,
      Wp, bs[0], bs[1], bs[2], bs[3], out);
}